// Round 8
// baseline (1097.830 us; speedup 1.0000x reference)
//
#include <hip/hip_runtime.h>
#include <math.h>

// Problem constants: B=8, N=M=2048, D=3.
#define BB 8
#define NN 2048
#define L2E 1.4426950408889634f
#define LN2 0.6931471805599453f
#define PI_F 3.14159265358979f
#define CLIP 0.999999f

typedef float f2 __attribute__((ext_vector_type(2)));

constexpr int TB   = 128;
constexpr int T16  = NN / TB;              // 16
constexpr int NXX  = T16 * (T16 + 1) / 2;  // 136
constexpr int NT   = 2 * NXX + T16 * T16;  // 528 tiles per batch
constexpr int SARR = BB * NN;              // 16384

// tile index -> (kind, I, J). kind 0: xx (I<=J), 1: yy (I<=J), 2: xy (all)
__device__ __forceinline__ void decode_tile(int bx, int& kind, int& I, int& J) {
    if (bx < NXX) kind = 0;
    else if (bx < 2 * NXX) { kind = 1; bx -= NXX; }
    else { kind = 2; bx -= 2 * NXX; }
    if (kind < 2) {
        int idx = bx; I = 0;
        for (;;) { int len = T16 - I; if (idx < len) { J = I + idx; break; } idx -= len; I++; }
    } else { I = bx >> 4; J = bx & 15; }
}

// raw acos via A&S 4.4.45 (|err| <= 7e-5 rad), input pre-clipped
__device__ __forceinline__ float acos_raw(float d) {
    const float u = fabsf(d);
    float pl = fmaf(u, -0.0187293f, 0.0742610f);
    pl = fmaf(u, pl, -0.2121144f); pl = fmaf(u, pl, 1.5707288f);
    const float rt = __builtin_amdgcn_sqrtf(1.f - u) * pl;
    return (d >= 0.f) ? rt : (PI_F - rt);
}

// ---------------------------------------------------------------------------
// pack: initial g = log_weights * log2(e); emit W = 2^{g-G}, per-128-block G.
// o in {0:a_x(x),1:b_y(y),2:a_y-side(y),3:b_x-side(x)}
// ---------------------------------------------------------------------------
__global__ __launch_bounds__(256)
void pack_kernel(const float* __restrict__ alpha, const float* __restrict__ beta,
                 float* __restrict__ gxw, float* __restrict__ gyw,
                 float* __restrict__ Wall, float* __restrict__ Gall)
{
    const int tid = threadIdx.x;
    const int gid = blockIdx.x * 256 + tid;
    const int o = gid >> 14, i = gid & (SARR - 1);
    const float* w = (o == 0 || o == 3) ? alpha : beta;
    const float v = w[i];
    const float g = ((v > 0.f) ? logf(fmaxf(v, 1e-30f)) : -1e5f) * L2E;
    if (o == 0) gxw[i] = g;
    if (o == 1) gyw[i] = g;
    __shared__ float red[256];
    red[tid] = g;
    __syncthreads();
    const int base = tid & 128, loc = tid & 127;
    for (int st = 64; st; st >>= 1) {
        if (loc < st) red[base + loc] = fmaxf(red[base + loc], red[base + loc + st]);
        __syncthreads();
    }
    const float G = red[base];
    Wall[gid] = __builtin_amdgcn_exp2f(g - G);
    if (loc == 0) Gall[gid >> 7] = G;
}

// ---------------------------------------------------------------------------
// One-time geometry pass over FULL tile grids (kind = blockIdx.z).
// Stores THETA of the per-row / per-col max-dot (eps-independent), so the
// per-step staging is a single multiply.
// ---------------------------------------------------------------------------
__global__ __launch_bounds__(256)
void maxes_kernel(const float* __restrict__ x, const float* __restrict__ y,
                  float* __restrict__ Rxx, float* __restrict__ Ryy,
                  float* __restrict__ Rxy, float* __restrict__ Cxy)
{
    __shared__ float4 p1s[TB], p2s[TB];
    __shared__ float colred[4][TB];
    const int I = blockIdx.x >> 4, J = blockIdx.x & 15;
    const int b = blockIdx.y, kind = blockIdx.z, t = threadIdx.x;
    const float* P1 = (kind == 1) ? y : x;
    const float* P2 = (kind == 0) ? x : y;
    if (t < TB) {
        size_t gi = (size_t)b * NN + (size_t)I * TB + t;
        p1s[t] = make_float4(P1[gi * 3], P1[gi * 3 + 1], P1[gi * 3 + 2], 0.f);
    } else {
        int u = t - TB; size_t gi = (size_t)b * NN + (size_t)J * TB + u;
        p2s[u] = make_float4(P2[gi * 3], P2[gi * 3 + 1], P2[gi * 3 + 2], 0.f);
    }
    __syncthreads();
    const int lane = t & 63, wv = t >> 6, colg = lane & 7, rowg = lane >> 3;
    const int r0 = wv * 32 + rowg * 4;
    float4 pr[4];
#pragma unroll
    for (int rr = 0; rr < 4; rr++) pr[rr] = p1s[r0 + rr];
    float rmx[4] = {-2.f, -2.f, -2.f, -2.f};
    float cmx[16];
#pragma unroll
    for (int j = 0; j < 16; j++) cmx[j] = -2.f;
#pragma unroll
    for (int j = 0; j < 16; j++) {
        const float4 q = p2s[colg + 8 * j];
#pragma unroll
        for (int rr = 0; rr < 4; rr++) {
            float d = fmaf(pr[rr].x, q.x, fmaf(pr[rr].y, q.y, pr[rr].z * q.z));
            rmx[rr] = fmaxf(rmx[rr], d);
            cmx[j] = fmaxf(cmx[j], d);
        }
    }
#pragma unroll
    for (int rr = 0; rr < 4; rr++) {
        float v = rmx[rr];
        v = fmaxf(v, __shfl_xor(v, 1)); v = fmaxf(v, __shfl_xor(v, 2));
        v = fmaxf(v, __shfl_xor(v, 4));
        rmx[rr] = v;
    }
    if (colg == 0) {
        float* R = (kind == 0) ? Rxx : (kind == 1) ? Ryy : Rxy;
        const size_t base = ((size_t)b * T16 + J) * NN + (size_t)I * TB + r0;
#pragma unroll
        for (int rr = 0; rr < 4; rr++)
            R[base + rr] = acos_raw(fminf(fmaxf(rmx[rr], -CLIP), CLIP));
    }
    if (kind == 2) {
#pragma unroll
        for (int j = 0; j < 16; j++) {
            float v = cmx[j];
            v = fmaxf(v, __shfl_xor(v, 8)); v = fmaxf(v, __shfl_xor(v, 16));
            v = fmaxf(v, __shfl_xor(v, 32));
            cmx[j] = v;
        }
        if (rowg == 0) {
#pragma unroll
            for (int j = 0; j < 16; j++) colred[wv][colg + 8 * j] = cmx[j];
        }
        __syncthreads();
        if (t < TB) {
            const float v = fmaxf(fmaxf(colred[0][t], colred[1][t]),
                                  fmaxf(colred[2][t], colred[3][t]));
            Cxy[((size_t)b * T16 + I) * NN + (size_t)J * TB + t] =
                acos_raw(fminf(fmaxf(v, -CLIP), CLIP));
        }
    }
}

// ---------------------------------------------------------------------------
// Tile kernel (packed-FP32): row pairs processed as float2 so the dot/poly/
// arg arithmetic can lower to v_pk_fma_f32. ach computed once per pair; two
// exp2 serve the two reduction directions with per-row / per-col shifts.
// ---------------------------------------------------------------------------
struct TileArgs {
    const float* x; const float* y;
    const float* Wall; const float* Gall;
    const float* Rxx; const float* Ryy; const float* Rxy; const float* Cxy;
    float2* pAX; float2* pBY; float2* pAY; float2* pBX;
};

__global__ __launch_bounds__(256, 6)
void tile_kernel(TileArgs A, float ieh, float pi_ieh)
{
    __shared__ float4 p1s[TB], p2s[TB];   // {px,py,pz,W}
    __shared__ float srs[TB], scs[TB];    // per-row / per-col shifts (scaled)
    __shared__ float colpart[4][TB];
    int kind, I, J; decode_tile(blockIdx.x, kind, I, J);
    const int b = blockIdx.y, t = threadIdx.x;
    const float* P1 = (kind == 1) ? A.y : A.x;
    const float* P2 = (kind == 0) ? A.x : A.y;
    const int o1 = (kind == 0) ? 0 : (kind == 1) ? 1 : 3;
    const int o2 = (kind == 0) ? 0 : (kind == 1) ? 1 : 2;
    float2* rowOut = (kind == 0) ? A.pAX : (kind == 1) ? A.pBY : A.pBX;
    float2* colOut = (kind == 0) ? A.pAX : (kind == 1) ? A.pBY : A.pAY;
    const bool diag = (kind < 2) && (I == J);
    const float* W1 = A.Wall + (size_t)o1 * SARR;
    const float* W2 = A.Wall + (size_t)o2 * SARR;
    const float* Rrow = (kind == 0) ? A.Rxx : (kind == 1) ? A.Ryy : A.Rxy;
    const float* Csrc = (kind == 0) ? A.Rxx : (kind == 1) ? A.Ryy : A.Cxy;

    // acos poly coefficients pre-scaled by ieh (log2 domain)
    const float K0 = 1.5707288f * ieh, K1 = -0.2121144f * ieh;
    const float K2 = 0.0742610f * ieh, K3 = -0.0187293f * ieh;

    if (t < TB) {
        size_t gi = (size_t)b * NN + (size_t)I * TB + t;
        p1s[t] = make_float4(P1[gi * 3], P1[gi * 3 + 1], P1[gi * 3 + 2], W1[gi]);
        srs[t] = Rrow[((size_t)b * T16 + J) * NN + (size_t)I * TB + t] * ieh;
    } else {
        int u = t - TB; size_t gi = (size_t)b * NN + (size_t)J * TB + u;
        p2s[u] = make_float4(P2[gi * 3], P2[gi * 3 + 1], P2[gi * 3 + 2], W2[gi]);
        scs[u] = Csrc[((size_t)b * T16 + I) * NN + (size_t)J * TB + u] * ieh;
    }
    const float G1 = A.Gall[o1 * 128 + b * T16 + I];
    const float G2 = A.Gall[o2 * 128 + b * T16 + J];
    __syncthreads();

    const int lane = t & 63, wv = t >> 6, colg = lane & 7, rowg = lane >> 3;
    const int r0 = wv * 32 + rowg * 4;

    // row-pair registers (g = 0: rows r0,r0+1; g = 1: rows r0+2,r0+3)
    f2 px[2], py[2], pz[2], w1v[2], sr2[2];
#pragma unroll
    for (int g = 0; g < 2; g++) {
        const float4 a0 = p1s[r0 + 2 * g], a1 = p1s[r0 + 2 * g + 1];
        px[g] = (f2){a0.x, a1.x}; py[g] = (f2){a0.y, a1.y}; pz[g] = (f2){a0.z, a1.z};
        w1v[g] = (f2){a0.w, a1.w};
        sr2[g] = (f2){srs[r0 + 2 * g], srs[r0 + 2 * g + 1]};
    }
    const f2 K3v = (f2){K3, K3}, K2v = (f2){K2, K2}, K1v = (f2){K1, K1}, K0v = (f2){K0, K0};
    const f2 onev = (f2){1.f, 1.f}, clipv = (f2){CLIP, CLIP};

    f2 racc2[2] = {(f2){0.f, 0.f}, (f2){0.f, 0.f}};
    float cacc[16];
#pragma unroll
    for (int j = 0; j < 16; j++) cacc[j] = 0.f;

#pragma unroll
    for (int j = 0; j < 16; j++) {
        const float4 q = p2s[colg + 8 * j];
        const float sc = scs[colg + 8 * j];
        const f2 qx = (f2){q.x, q.x}, qy = (f2){q.y, q.y}, qz = (f2){q.z, q.z};
        const f2 w2v = (f2){q.w, q.w}, scv = (f2){sc, sc};
#pragma unroll
        for (int g = 0; g < 2; g++) {
            f2 d = __builtin_elementwise_fma(px[g], qx,
                    __builtin_elementwise_fma(py[g], qy, pz[g] * qz));
            f2 u = __builtin_elementwise_min(__builtin_elementwise_abs(d), clipv);
            f2 pl = __builtin_elementwise_fma(u, K3v, K2v);
            pl = __builtin_elementwise_fma(u, pl, K1v);
            pl = __builtin_elementwise_fma(u, pl, K0v);
            f2 om = onev - u;
            f2 rt;
            rt.x = __builtin_amdgcn_sqrtf(om.x);
            rt.y = __builtin_amdgcn_sqrtf(om.y);
            f2 th = rt * pl;
            f2 ach;
            ach.x = (d.x >= 0.f) ? th.x : (pi_ieh - th.x);
            ach.y = (d.y >= 0.f) ? th.y : (pi_ieh - th.y);
            f2 ar = sr2[g] - ach;
            f2 ac = scv - ach;
            f2 er, ec;
            er.x = __builtin_amdgcn_exp2f(ar.x);
            er.y = __builtin_amdgcn_exp2f(ar.y);
            ec.x = __builtin_amdgcn_exp2f(ac.x);
            ec.y = __builtin_amdgcn_exp2f(ac.y);
            racc2[g] = __builtin_elementwise_fma(w2v, er, racc2[g]);
            cacc[j] = fmaf(w1v[g].x, ec.x, fmaf(w1v[g].y, ec.y, cacc[j]));
        }
    }

    // col sums: reduce across rowg (lane bits 3..5)
#pragma unroll
    for (int j = 0; j < 16; j++) {
        float v = cacc[j];
        v += __shfl_xor(v, 8); v += __shfl_xor(v, 16); v += __shfl_xor(v, 32);
        cacc[j] = v;
    }
    if (rowg == 0) {
#pragma unroll
        for (int j = 0; j < 16; j++) colpart[wv][colg + 8 * j] = cacc[j];
    }
    // row sums: reduce across colg (lane bits 0..2)
    float racc[4] = {racc2[0].x, racc2[0].y, racc2[1].x, racc2[1].y};
    float srr[4] = {sr2[0].x, sr2[0].y, sr2[1].x, sr2[1].y};
#pragma unroll
    for (int rr = 0; rr < 4; rr++) {
        float v = racc[rr];
        v += __shfl_xor(v, 1); v += __shfl_xor(v, 2); v += __shfl_xor(v, 4);
        racc[rr] = v;
    }
    if (colg == 0) {
        const size_t gr = (size_t)b * NN + (size_t)I * TB + r0;
#pragma unroll
        for (int rr = 0; rr < 4; rr++)
            rowOut[(gr + rr) * T16 + J] = make_float2(G2 - srr[rr], racc[rr]);
    }
    __syncthreads();
    if (!diag && t < TB) {
        const float v = colpart[0][t] + colpart[1][t] + colpart[2][t] + colpart[3][t];
        const size_t gc = (size_t)b * NN + (size_t)J * TB + t;
        colOut[gc * T16 + I] = make_float2(G1 - scs[t], v);
    }
}

// ---------------------------------------------------------------------------
// combine: merge 16 (M,S) partials per row; r = -eps*ln2*(M+log2 S); optional
// 0.5-averaging; emit next-step W = 2^{g-G} and per-block G.
// ---------------------------------------------------------------------------
__global__ __launch_bounds__(256)
void combine_kernel(const float2* __restrict__ pAX, const float2* __restrict__ pBY,
                    const float2* __restrict__ pAY, const float2* __restrict__ pBX,
                    float* __restrict__ ax, float* __restrict__ by,
                    float* __restrict__ ay, float* __restrict__ bx,
                    const float* __restrict__ gxw, const float* __restrict__ gyw,
                    float* __restrict__ Wall, float* __restrict__ Gall,
                    float eps_ln2, float nieL2E, int do_avg)
{
    const int tid = threadIdx.x;
    const int gid = blockIdx.x * 256 + tid;
    const int o = gid >> 14, i = gid & (SARR - 1);
    const float2* P = (o == 0) ? pAX : (o == 1) ? pBY : (o == 2) ? pAY : pBX;
    float* pot = (o == 0) ? ax : (o == 1) ? by : (o == 2) ? ay : bx;
    const float2* row = P + (size_t)i * T16;
    float M = -INFINITY, S = 0.f;
#pragma unroll
    for (int u = 0; u < T16; u++) {
        const float2 pr = row[u];
        if (pr.y > 0.f) {
            const float nm = fmaxf(M, pr.x);
            S = S * __builtin_amdgcn_exp2f(M - nm) + pr.y * __builtin_amdgcn_exp2f(pr.x - nm);
            M = nm;
        }
    }
    S = fmaxf(S, 1e-38f);
    float r = -eps_ln2 * (M + __builtin_amdgcn_logf(S));
    if (do_avg) r = 0.5f * (r + pot[i]);
    pot[i] = r;
    const float g = ((o == 0 || o == 3) ? gxw[i] : gyw[i]) + r * nieL2E;
    __shared__ float red[256];
    red[tid] = g;
    __syncthreads();
    const int base = tid & 128, loc = tid & 127;
    for (int st = 64; st; st >>= 1) {
        if (loc < st) red[base + loc] = fmaxf(red[base + loc], red[base + loc + st]);
        __syncthreads();
    }
    const float G = red[base];
    Wall[gid] = __builtin_amdgcn_exp2f(g - G);
    if (loc == 0) Gall[gid >> 7] = G;
}

// ---------------------------------------------------------------------------
__global__ __launch_bounds__(256)
void reduce_kernel(const float* __restrict__ alpha, const float* __restrict__ beta,
                   const float* __restrict__ a_x, const float* __restrict__ b_x,
                   const float* __restrict__ a_y, const float* __restrict__ b_y,
                   float* __restrict__ out)
{
    const int b = blockIdx.x, tid = threadIdx.x;
    float acc = 0.f;
    for (int n = tid; n < NN; n += 256) {
        const size_t i = (size_t)b * NN + n;
        acc += alpha[i] * (b_x[i] - a_x[i]);
        acc += beta[i] * (a_y[i] - b_y[i]);
    }
    __shared__ float red[256];
    red[tid] = acc;
    __syncthreads();
    for (int st = 128; st > 0; st >>= 1) {
        if (tid < st) red[tid] += red[tid + st];
        __syncthreads();
    }
    if (tid == 0) out[b] = red[0];
}

// ---------------------------------------------------------------------------
extern "C" void kernel_launch(void* const* d_in, const int* in_sizes, int n_in,
                              void* d_out, int out_size, void* d_ws, size_t ws_size,
                              hipStream_t stream)
{
    const float* alpha = (const float*)d_in[0];
    const float* x     = (const float*)d_in[1];
    const float* beta  = (const float*)d_in[2];
    const float* y     = (const float*)d_in[3];
    float* out = (float*)d_out;
    float* ws  = (float*)d_ws;

    const size_t S = SARR;
    float* gxw  = ws;
    float* gyw  = ws + S;
    float* ax   = ws + 2 * S;
    float* by   = ws + 3 * S;
    float* ay   = ws + 4 * S;
    float* bx   = ws + 5 * S;
    float* Wall = ws + 6 * S;              // 4*S
    float* Gall = ws + 10 * S;             // 512
    float* Rxx  = ws + 10 * S + 512;       // 16*S each (theta of max-dot)
    float* Ryy  = Rxx + 16 * S;
    float* Rxy  = Ryy + 16 * S;
    float* Cxy  = Rxy + 16 * S;
    float* pb   = Cxy + 16 * S;
    const size_t PSZ = (size_t)SARR * T16;
    float2* pAX = (float2*)pb;
    float2* pBY = pAX + PSZ;
    float2* pAY = pBY + PSZ;
    float2* pBX = pAY + PSZ;

    const float EPS[8] = {4.0f, 4.0f, 1.0f, 0.25f, 0.0625f, 0.015625f, 0.00390625f, 0.0025f};

    pack_kernel<<<(4 * SARR) / 256, 256, 0, stream>>>(alpha, beta, gxw, gyw, Wall, Gall);
    maxes_kernel<<<dim3(256, BB, 3), 256, 0, stream>>>(x, y, Rxx, Ryy, Rxy, Cxy);

    TileArgs TA;
    TA.x = x; TA.y = y; TA.Wall = Wall; TA.Gall = Gall;
    TA.Rxx = Rxx; TA.Ryy = Ryy; TA.Rxy = Rxy; TA.Cxy = Cxy;
    TA.pAX = pAX; TA.pBY = pBY; TA.pAY = pAY; TA.pBX = pBX;

    auto step = [&](float e, float next_e, int avg) {
        const float ieh = 0.5f * (1.f / e) * L2E;
        tile_kernel<<<dim3(NT, BB), 256, 0, stream>>>(TA, ieh, PI_F * ieh);
        combine_kernel<<<(4 * SARR) / 256, 256, 0, stream>>>(
            pAX, pBY, pAY, pBX, ax, by, ay, bx, gxw, gyw, Wall, Gall,
            e * LN2, (1.f / next_e) * L2E, avg);
    };

    step(EPS[0], EPS[0], 0);                                   // init
    for (int k = 0; k < 8; k++) step(EPS[k], (k < 7) ? EPS[k + 1] : EPS[7], 1);
    step(EPS[7], EPS[7], 0);                                   // final extrapolation

    reduce_kernel<<<BB, 256, 0, stream>>>(alpha, beta, ax, bx, ay, by, out);
}

// Round 9
// 697.593 us; speedup vs baseline: 1.5737x; 1.5737x over previous
//
#include <hip/hip_runtime.h>
#include <math.h>

// Problem constants: B=8, N=M=2048, D=3.
#define BB 8
#define NN 2048
#define L2E 1.4426950408889634f
#define LN2 0.6931471805599453f
#define PI_F 3.14159265358979f
#define CLIP 0.999999f

typedef float f2 __attribute__((ext_vector_type(2)));

constexpr int TB   = 128;
constexpr int T16  = NN / TB;              // 16
constexpr int NXX  = T16 * (T16 + 1) / 2;  // 136
constexpr int NT   = 2 * NXX + T16 * T16;  // 528 tiles per batch
constexpr int SARR = BB * NN;              // 16384

// tile index -> (kind, I, J). kind 0: xx (I<=J), 1: yy (I<=J), 2: xy (all)
__device__ __forceinline__ void decode_tile(int bx, int& kind, int& I, int& J) {
    if (bx < NXX) kind = 0;
    else if (bx < 2 * NXX) { kind = 1; bx -= NXX; }
    else { kind = 2; bx -= 2 * NXX; }
    if (kind < 2) {
        int idx = bx; I = 0;
        for (;;) { int len = T16 - I; if (idx < len) { J = I + idx; break; } idx -= len; I++; }
    } else { I = bx >> 4; J = bx & 15; }
}

// raw acos via A&S 4.4.45 (|err| <= 7e-5 rad), input pre-clipped
__device__ __forceinline__ float acos_raw(float d) {
    const float u = fabsf(d);
    float pl = fmaf(u, -0.0187293f, 0.0742610f);
    pl = fmaf(u, pl, -0.2121144f); pl = fmaf(u, pl, 1.5707288f);
    const float rt = __builtin_amdgcn_sqrtf(1.f - u) * pl;
    return (d >= 0.f) ? rt : (PI_F - rt);
}

// ---------------------------------------------------------------------------
// pack: initial g = log_weights * log2(e); emit W = 2^{g-G}, per-128-block G.
// o in {0:a_x(x),1:b_y(y),2:a_y-side(y),3:b_x-side(x)}
// ---------------------------------------------------------------------------
__global__ __launch_bounds__(256)
void pack_kernel(const float* __restrict__ alpha, const float* __restrict__ beta,
                 float* __restrict__ gxw, float* __restrict__ gyw,
                 float* __restrict__ Wall, float* __restrict__ Gall)
{
    const int tid = threadIdx.x;
    const int gid = blockIdx.x * 256 + tid;
    const int o = gid >> 14, i = gid & (SARR - 1);
    const float* w = (o == 0 || o == 3) ? alpha : beta;
    const float v = w[i];
    const float g = ((v > 0.f) ? logf(fmaxf(v, 1e-30f)) : -1e5f) * L2E;
    if (o == 0) gxw[i] = g;
    if (o == 1) gyw[i] = g;
    __shared__ float red[256];
    red[tid] = g;
    __syncthreads();
    const int base = tid & 128, loc = tid & 127;
    for (int st = 64; st; st >>= 1) {
        if (loc < st) red[base + loc] = fmaxf(red[base + loc], red[base + loc + st]);
        __syncthreads();
    }
    const float G = red[base];
    Wall[gid] = __builtin_amdgcn_exp2f(g - G);
    if (loc == 0) Gall[gid >> 7] = G;
}

// ---------------------------------------------------------------------------
// One-time geometry pass over FULL tile grids (kind = blockIdx.z).
// Stores THETA of the per-row / per-col max-dot (eps-independent), so the
// per-step staging is a single multiply.
// ---------------------------------------------------------------------------
__global__ __launch_bounds__(256)
void maxes_kernel(const float* __restrict__ x, const float* __restrict__ y,
                  float* __restrict__ Rxx, float* __restrict__ Ryy,
                  float* __restrict__ Rxy, float* __restrict__ Cxy)
{
    __shared__ float4 p1s[TB], p2s[TB];
    __shared__ float colred[4][TB];
    const int I = blockIdx.x >> 4, J = blockIdx.x & 15;
    const int b = blockIdx.y, kind = blockIdx.z, t = threadIdx.x;
    const float* P1 = (kind == 1) ? y : x;
    const float* P2 = (kind == 0) ? x : y;
    if (t < TB) {
        size_t gi = (size_t)b * NN + (size_t)I * TB + t;
        p1s[t] = make_float4(P1[gi * 3], P1[gi * 3 + 1], P1[gi * 3 + 2], 0.f);
    } else {
        int u = t - TB; size_t gi = (size_t)b * NN + (size_t)J * TB + u;
        p2s[u] = make_float4(P2[gi * 3], P2[gi * 3 + 1], P2[gi * 3 + 2], 0.f);
    }
    __syncthreads();
    const int lane = t & 63, wv = t >> 6, colg = lane & 7, rowg = lane >> 3;
    const int r0 = wv * 32 + rowg * 4;
    float4 pr[4];
#pragma unroll
    for (int rr = 0; rr < 4; rr++) pr[rr] = p1s[r0 + rr];
    float rmx[4] = {-2.f, -2.f, -2.f, -2.f};
    float cmx[16];
#pragma unroll
    for (int j = 0; j < 16; j++) cmx[j] = -2.f;
#pragma unroll
    for (int j = 0; j < 16; j++) {
        const float4 q = p2s[colg + 8 * j];
#pragma unroll
        for (int rr = 0; rr < 4; rr++) {
            float d = fmaf(pr[rr].x, q.x, fmaf(pr[rr].y, q.y, pr[rr].z * q.z));
            rmx[rr] = fmaxf(rmx[rr], d);
            cmx[j] = fmaxf(cmx[j], d);
        }
    }
#pragma unroll
    for (int rr = 0; rr < 4; rr++) {
        float v = rmx[rr];
        v = fmaxf(v, __shfl_xor(v, 1)); v = fmaxf(v, __shfl_xor(v, 2));
        v = fmaxf(v, __shfl_xor(v, 4));
        rmx[rr] = v;
    }
    if (colg == 0) {
        float* R = (kind == 0) ? Rxx : (kind == 1) ? Ryy : Rxy;
        const size_t base = ((size_t)b * T16 + J) * NN + (size_t)I * TB + r0;
#pragma unroll
        for (int rr = 0; rr < 4; rr++)
            R[base + rr] = acos_raw(fminf(fmaxf(rmx[rr], -CLIP), CLIP));
    }
    if (kind == 2) {
#pragma unroll
        for (int j = 0; j < 16; j++) {
            float v = cmx[j];
            v = fmaxf(v, __shfl_xor(v, 8)); v = fmaxf(v, __shfl_xor(v, 16));
            v = fmaxf(v, __shfl_xor(v, 32));
            cmx[j] = v;
        }
        if (rowg == 0) {
#pragma unroll
            for (int j = 0; j < 16; j++) colred[wv][colg + 8 * j] = cmx[j];
        }
        __syncthreads();
        if (t < TB) {
            const float v = fmaxf(fmaxf(colred[0][t], colred[1][t]),
                                  fmaxf(colred[2][t], colred[3][t]));
            Cxy[((size_t)b * T16 + I) * NN + (size_t)J * TB + t] =
                acos_raw(fminf(fmaxf(v, -CLIP), CLIP));
        }
    }
}

// ---------------------------------------------------------------------------
// Tile kernel (packed-FP32): row pairs processed as float2 so the dot/poly/
// arg arithmetic can lower to v_pk_fma_f32. ach computed once per pair; two
// exp2 serve the two reduction directions with per-row / per-col shifts.
// NOTE: no min-waves in launch_bounds — forcing 6 waves/EU capped the
// allocator at 40 VGPRs and spilled 450 MB/dispatch to scratch (round 8).
// ---------------------------------------------------------------------------
struct TileArgs {
    const float* x; const float* y;
    const float* Wall; const float* Gall;
    const float* Rxx; const float* Ryy; const float* Rxy; const float* Cxy;
    float2* pAX; float2* pBY; float2* pAY; float2* pBX;
};

__global__ __launch_bounds__(256)
void tile_kernel(TileArgs A, float ieh, float pi_ieh)
{
    __shared__ float4 p1s[TB], p2s[TB];   // {px,py,pz,W}
    __shared__ float srs[TB], scs[TB];    // per-row / per-col shifts (scaled)
    __shared__ float colpart[4][TB];
    int kind, I, J; decode_tile(blockIdx.x, kind, I, J);
    const int b = blockIdx.y, t = threadIdx.x;
    const float* P1 = (kind == 1) ? A.y : A.x;
    const float* P2 = (kind == 0) ? A.x : A.y;
    const int o1 = (kind == 0) ? 0 : (kind == 1) ? 1 : 3;
    const int o2 = (kind == 0) ? 0 : (kind == 1) ? 1 : 2;
    float2* rowOut = (kind == 0) ? A.pAX : (kind == 1) ? A.pBY : A.pBX;
    float2* colOut = (kind == 0) ? A.pAX : (kind == 1) ? A.pBY : A.pAY;
    const bool diag = (kind < 2) && (I == J);
    const float* W1 = A.Wall + (size_t)o1 * SARR;
    const float* W2 = A.Wall + (size_t)o2 * SARR;
    const float* Rrow = (kind == 0) ? A.Rxx : (kind == 1) ? A.Ryy : A.Rxy;
    const float* Csrc = (kind == 0) ? A.Rxx : (kind == 1) ? A.Ryy : A.Cxy;

    // acos poly coefficients pre-scaled by ieh (log2 domain)
    const float K0 = 1.5707288f * ieh, K1 = -0.2121144f * ieh;
    const float K2 = 0.0742610f * ieh, K3 = -0.0187293f * ieh;

    if (t < TB) {
        size_t gi = (size_t)b * NN + (size_t)I * TB + t;
        p1s[t] = make_float4(P1[gi * 3], P1[gi * 3 + 1], P1[gi * 3 + 2], W1[gi]);
        srs[t] = Rrow[((size_t)b * T16 + J) * NN + (size_t)I * TB + t] * ieh;
    } else {
        int u = t - TB; size_t gi = (size_t)b * NN + (size_t)J * TB + u;
        p2s[u] = make_float4(P2[gi * 3], P2[gi * 3 + 1], P2[gi * 3 + 2], W2[gi]);
        scs[u] = Csrc[((size_t)b * T16 + I) * NN + (size_t)J * TB + u] * ieh;
    }
    const float G1 = A.Gall[o1 * 128 + b * T16 + I];
    const float G2 = A.Gall[o2 * 128 + b * T16 + J];
    __syncthreads();

    const int lane = t & 63, wv = t >> 6, colg = lane & 7, rowg = lane >> 3;
    const int r0 = wv * 32 + rowg * 4;

    // row-pair registers (g = 0: rows r0,r0+1; g = 1: rows r0+2,r0+3)
    f2 px[2], py[2], pz[2], w1v[2], sr2[2];
#pragma unroll
    for (int g = 0; g < 2; g++) {
        const float4 a0 = p1s[r0 + 2 * g], a1 = p1s[r0 + 2 * g + 1];
        px[g] = (f2){a0.x, a1.x}; py[g] = (f2){a0.y, a1.y}; pz[g] = (f2){a0.z, a1.z};
        w1v[g] = (f2){a0.w, a1.w};
        sr2[g] = (f2){srs[r0 + 2 * g], srs[r0 + 2 * g + 1]};
    }
    const f2 K3v = (f2){K3, K3}, K2v = (f2){K2, K2}, K1v = (f2){K1, K1}, K0v = (f2){K0, K0};
    const f2 onev = (f2){1.f, 1.f}, clipv = (f2){CLIP, CLIP};

    f2 racc2[2] = {(f2){0.f, 0.f}, (f2){0.f, 0.f}};
    float cacc[16];
#pragma unroll
    for (int j = 0; j < 16; j++) cacc[j] = 0.f;

#pragma unroll
    for (int j = 0; j < 16; j++) {
        const float4 q = p2s[colg + 8 * j];
        const float sc = scs[colg + 8 * j];
        const f2 qx = (f2){q.x, q.x}, qy = (f2){q.y, q.y}, qz = (f2){q.z, q.z};
        const f2 w2v = (f2){q.w, q.w}, scv = (f2){sc, sc};
#pragma unroll
        for (int g = 0; g < 2; g++) {
            f2 d = __builtin_elementwise_fma(px[g], qx,
                    __builtin_elementwise_fma(py[g], qy, pz[g] * qz));
            f2 u = __builtin_elementwise_min(__builtin_elementwise_abs(d), clipv);
            f2 pl = __builtin_elementwise_fma(u, K3v, K2v);
            pl = __builtin_elementwise_fma(u, pl, K1v);
            pl = __builtin_elementwise_fma(u, pl, K0v);
            f2 om = onev - u;
            f2 rt;
            rt.x = __builtin_amdgcn_sqrtf(om.x);
            rt.y = __builtin_amdgcn_sqrtf(om.y);
            f2 th = rt * pl;
            f2 ach;
            ach.x = (d.x >= 0.f) ? th.x : (pi_ieh - th.x);
            ach.y = (d.y >= 0.f) ? th.y : (pi_ieh - th.y);
            f2 ar = sr2[g] - ach;
            f2 ac = scv - ach;
            f2 er, ec;
            er.x = __builtin_amdgcn_exp2f(ar.x);
            er.y = __builtin_amdgcn_exp2f(ar.y);
            ec.x = __builtin_amdgcn_exp2f(ac.x);
            ec.y = __builtin_amdgcn_exp2f(ac.y);
            racc2[g] = __builtin_elementwise_fma(w2v, er, racc2[g]);
            cacc[j] = fmaf(w1v[g].x, ec.x, fmaf(w1v[g].y, ec.y, cacc[j]));
        }
    }

    // col sums: reduce across rowg (lane bits 3..5)
#pragma unroll
    for (int j = 0; j < 16; j++) {
        float v = cacc[j];
        v += __shfl_xor(v, 8); v += __shfl_xor(v, 16); v += __shfl_xor(v, 32);
        cacc[j] = v;
    }
    if (rowg == 0) {
#pragma unroll
        for (int j = 0; j < 16; j++) colpart[wv][colg + 8 * j] = cacc[j];
    }
    // row sums: reduce across colg (lane bits 0..2)
    float racc[4] = {racc2[0].x, racc2[0].y, racc2[1].x, racc2[1].y};
    float srr[4] = {sr2[0].x, sr2[0].y, sr2[1].x, sr2[1].y};
#pragma unroll
    for (int rr = 0; rr < 4; rr++) {
        float v = racc[rr];
        v += __shfl_xor(v, 1); v += __shfl_xor(v, 2); v += __shfl_xor(v, 4);
        racc[rr] = v;
    }
    if (colg == 0) {
        const size_t gr = (size_t)b * NN + (size_t)I * TB + r0;
#pragma unroll
        for (int rr = 0; rr < 4; rr++)
            rowOut[(gr + rr) * T16 + J] = make_float2(G2 - srr[rr], racc[rr]);
    }
    __syncthreads();
    if (!diag && t < TB) {
        const float v = colpart[0][t] + colpart[1][t] + colpart[2][t] + colpart[3][t];
        const size_t gc = (size_t)b * NN + (size_t)J * TB + t;
        colOut[gc * T16 + I] = make_float2(G1 - scs[t], v);
    }
}

// ---------------------------------------------------------------------------
// combine: merge 16 (M,S) partials per row; r = -eps*ln2*(M+log2 S); optional
// 0.5-averaging; emit next-step W = 2^{g-G} and per-block G.
// ---------------------------------------------------------------------------
__global__ __launch_bounds__(256)
void combine_kernel(const float2* __restrict__ pAX, const float2* __restrict__ pBY,
                    const float2* __restrict__ pAY, const float2* __restrict__ pBX,
                    float* __restrict__ ax, float* __restrict__ by,
                    float* __restrict__ ay, float* __restrict__ bx,
                    const float* __restrict__ gxw, const float* __restrict__ gyw,
                    float* __restrict__ Wall, float* __restrict__ Gall,
                    float eps_ln2, float nieL2E, int do_avg)
{
    const int tid = threadIdx.x;
    const int gid = blockIdx.x * 256 + tid;
    const int o = gid >> 14, i = gid & (SARR - 1);
    const float2* P = (o == 0) ? pAX : (o == 1) ? pBY : (o == 2) ? pAY : pBX;
    float* pot = (o == 0) ? ax : (o == 1) ? by : (o == 2) ? ay : bx;
    const float2* row = P + (size_t)i * T16;
    float M = -INFINITY, S = 0.f;
#pragma unroll
    for (int u = 0; u < T16; u++) {
        const float2 pr = row[u];
        if (pr.y > 0.f) {
            const float nm = fmaxf(M, pr.x);
            S = S * __builtin_amdgcn_exp2f(M - nm) + pr.y * __builtin_amdgcn_exp2f(pr.x - nm);
            M = nm;
        }
    }
    S = fmaxf(S, 1e-38f);
    float r = -eps_ln2 * (M + __builtin_amdgcn_logf(S));
    if (do_avg) r = 0.5f * (r + pot[i]);
    pot[i] = r;
    const float g = ((o == 0 || o == 3) ? gxw[i] : gyw[i]) + r * nieL2E;
    __shared__ float red[256];
    red[tid] = g;
    __syncthreads();
    const int base = tid & 128, loc = tid & 127;
    for (int st = 64; st; st >>= 1) {
        if (loc < st) red[base + loc] = fmaxf(red[base + loc], red[base + loc + st]);
        __syncthreads();
    }
    const float G = red[base];
    Wall[gid] = __builtin_amdgcn_exp2f(g - G);
    if (loc == 0) Gall[gid >> 7] = G;
}

// ---------------------------------------------------------------------------
__global__ __launch_bounds__(256)
void reduce_kernel(const float* __restrict__ alpha, const float* __restrict__ beta,
                   const float* __restrict__ a_x, const float* __restrict__ b_x,
                   const float* __restrict__ a_y, const float* __restrict__ b_y,
                   float* __restrict__ out)
{
    const int b = blockIdx.x, tid = threadIdx.x;
    float acc = 0.f;
    for (int n = tid; n < NN; n += 256) {
        const size_t i = (size_t)b * NN + n;
        acc += alpha[i] * (b_x[i] - a_x[i]);
        acc += beta[i] * (a_y[i] - b_y[i]);
    }
    __shared__ float red[256];
    red[tid] = acc;
    __syncthreads();
    for (int st = 128; st > 0; st >>= 1) {
        if (tid < st) red[tid] += red[tid + st];
        __syncthreads();
    }
    if (tid == 0) out[b] = red[0];
}

// ---------------------------------------------------------------------------
extern "C" void kernel_launch(void* const* d_in, const int* in_sizes, int n_in,
                              void* d_out, int out_size, void* d_ws, size_t ws_size,
                              hipStream_t stream)
{
    const float* alpha = (const float*)d_in[0];
    const float* x     = (const float*)d_in[1];
    const float* beta  = (const float*)d_in[2];
    const float* y     = (const float*)d_in[3];
    float* out = (float*)d_out;
    float* ws  = (float*)d_ws;

    const size_t S = SARR;
    float* gxw  = ws;
    float* gyw  = ws + S;
    float* ax   = ws + 2 * S;
    float* by   = ws + 3 * S;
    float* ay   = ws + 4 * S;
    float* bx   = ws + 5 * S;
    float* Wall = ws + 6 * S;              // 4*S
    float* Gall = ws + 10 * S;             // 512
    float* Rxx  = ws + 10 * S + 512;       // 16*S each (theta of max-dot)
    float* Ryy  = Rxx + 16 * S;
    float* Rxy  = Ryy + 16 * S;
    float* Cxy  = Rxy + 16 * S;
    float* pb   = Cxy + 16 * S;
    const size_t PSZ = (size_t)SARR * T16;
    float2* pAX = (float2*)pb;
    float2* pBY = pAX + PSZ;
    float2* pAY = pBY + PSZ;
    float2* pBX = pAY + PSZ;

    const float EPS[8] = {4.0f, 4.0f, 1.0f, 0.25f, 0.0625f, 0.015625f, 0.00390625f, 0.0025f};

    pack_kernel<<<(4 * SARR) / 256, 256, 0, stream>>>(alpha, beta, gxw, gyw, Wall, Gall);
    maxes_kernel<<<dim3(256, BB, 3), 256, 0, stream>>>(x, y, Rxx, Ryy, Rxy, Cxy);

    TileArgs TA;
    TA.x = x; TA.y = y; TA.Wall = Wall; TA.Gall = Gall;
    TA.Rxx = Rxx; TA.Ryy = Ryy; TA.Rxy = Rxy; TA.Cxy = Cxy;
    TA.pAX = pAX; TA.pBY = pBY; TA.pAY = pAY; TA.pBX = pBX;

    auto step = [&](float e, float next_e, int avg) {
        const float ieh = 0.5f * (1.f / e) * L2E;
        tile_kernel<<<dim3(NT, BB), 256, 0, stream>>>(TA, ieh, PI_F * ieh);
        combine_kernel<<<(4 * SARR) / 256, 256, 0, stream>>>(
            pAX, pBY, pAY, pBX, ax, by, ay, bx, gxw, gyw, Wall, Gall,
            e * LN2, (1.f / next_e) * L2E, avg);
    };

    step(EPS[0], EPS[0], 0);                                   // init
    for (int k = 0; k < 8; k++) step(EPS[k], (k < 7) ? EPS[k + 1] : EPS[7], 1);
    step(EPS[7], EPS[7], 0);                                   // final extrapolation

    reduce_kernel<<<BB, 256, 0, stream>>>(alpha, beta, ax, bx, ay, by, out);
}

// Round 10
// 643.002 us; speedup vs baseline: 1.7074x; 1.0849x over previous
//
#include <hip/hip_runtime.h>
#include <math.h>

// Problem constants: B=8, N=M=2048, D=3.
#define BB 8
#define NN 2048
#define L2E 1.4426950408889634f
#define LN2 0.6931471805599453f
#define PI_F 3.14159265358979f
#define CLIP 0.999999f

constexpr int TB   = 128;
constexpr int T16  = NN / TB;              // 16
constexpr int NXX  = T16 * (T16 + 1) / 2;  // 136
constexpr int NT   = 2 * NXX + T16 * T16;  // 528 tiles per batch
constexpr int SARR = BB * NN;              // 16384

// tile index -> (kind, I, J). kind 0: xx (I<=J), 1: yy (I<=J), 2: xy (all)
__device__ __forceinline__ void decode_tile(int bx, int& kind, int& I, int& J) {
    if (bx < NXX) kind = 0;
    else if (bx < 2 * NXX) { kind = 1; bx -= NXX; }
    else { kind = 2; bx -= 2 * NXX; }
    if (kind < 2) {
        int idx = bx; I = 0;
        for (;;) { int len = T16 - I; if (idx < len) { J = I + idx; break; } idx -= len; I++; }
    } else { I = bx >> 4; J = bx & 15; }
}

// raw acos via A&S 4.4.45 (|err| <= 7e-5 rad), input pre-clipped
__device__ __forceinline__ float acos_raw(float d) {
    const float u = fabsf(d);
    float pl = fmaf(u, -0.0187293f, 0.0742610f);
    pl = fmaf(u, pl, -0.2121144f); pl = fmaf(u, pl, 1.5707288f);
    const float rt = __builtin_amdgcn_sqrtf(1.f - u) * pl;
    return (d >= 0.f) ? rt : (PI_F - rt);
}

// ---------------------------------------------------------------------------
// pack: initial g = log_weights * log2(e); emit W = 2^{g-G}, per-128-block G.
// o in {0:a_x(x),1:b_y(y),2:a_y-side(y),3:b_x-side(x)}
// ---------------------------------------------------------------------------
__global__ __launch_bounds__(256)
void pack_kernel(const float* __restrict__ alpha, const float* __restrict__ beta,
                 float* __restrict__ gxw, float* __restrict__ gyw,
                 float* __restrict__ Wall, float* __restrict__ Gall)
{
    const int tid = threadIdx.x;
    const int gid = blockIdx.x * 256 + tid;
    const int o = gid >> 14, i = gid & (SARR - 1);
    const float* w = (o == 0 || o == 3) ? alpha : beta;
    const float v = w[i];
    const float g = ((v > 0.f) ? logf(fmaxf(v, 1e-30f)) : -1e5f) * L2E;
    if (o == 0) gxw[i] = g;
    if (o == 1) gyw[i] = g;
    __shared__ float red[256];
    red[tid] = g;
    __syncthreads();
    const int base = tid & 128, loc = tid & 127;
    for (int st = 64; st; st >>= 1) {
        if (loc < st) red[base + loc] = fmaxf(red[base + loc], red[base + loc + st]);
        __syncthreads();
    }
    const float G = red[base];
    Wall[gid] = __builtin_amdgcn_exp2f(g - G);
    if (loc == 0) Gall[gid >> 7] = G;
}

// ---------------------------------------------------------------------------
// One-time geometry pass over FULL tile grids (kind = blockIdx.z).
// Stores THETA of the per-row / per-col max-dot (eps-independent), so the
// per-step staging is a single multiply.
// ---------------------------------------------------------------------------
__global__ __launch_bounds__(256)
void maxes_kernel(const float* __restrict__ x, const float* __restrict__ y,
                  float* __restrict__ Rxx, float* __restrict__ Ryy,
                  float* __restrict__ Rxy, float* __restrict__ Cxy)
{
    __shared__ float4 p1s[TB], p2s[TB];
    __shared__ float colred[4][TB];
    const int I = blockIdx.x >> 4, J = blockIdx.x & 15;
    const int b = blockIdx.y, kind = blockIdx.z, t = threadIdx.x;
    const float* P1 = (kind == 1) ? y : x;
    const float* P2 = (kind == 0) ? x : y;
    if (t < TB) {
        size_t gi = (size_t)b * NN + (size_t)I * TB + t;
        p1s[t] = make_float4(P1[gi * 3], P1[gi * 3 + 1], P1[gi * 3 + 2], 0.f);
    } else {
        int u = t - TB; size_t gi = (size_t)b * NN + (size_t)J * TB + u;
        p2s[u] = make_float4(P2[gi * 3], P2[gi * 3 + 1], P2[gi * 3 + 2], 0.f);
    }
    __syncthreads();
    const int lane = t & 63, wv = t >> 6, colg = lane & 7, rowg = lane >> 3;
    const int r0 = wv * 32 + rowg * 4;
    float4 pr[4];
#pragma unroll
    for (int rr = 0; rr < 4; rr++) pr[rr] = p1s[r0 + rr];
    float rmx[4] = {-2.f, -2.f, -2.f, -2.f};
    float cmx[16];
#pragma unroll
    for (int j = 0; j < 16; j++) cmx[j] = -2.f;
#pragma unroll
    for (int j = 0; j < 16; j++) {
        const float4 q = p2s[colg + 8 * j];
#pragma unroll
        for (int rr = 0; rr < 4; rr++) {
            float d = fmaf(pr[rr].x, q.x, fmaf(pr[rr].y, q.y, pr[rr].z * q.z));
            rmx[rr] = fmaxf(rmx[rr], d);
            cmx[j] = fmaxf(cmx[j], d);
        }
    }
#pragma unroll
    for (int rr = 0; rr < 4; rr++) {
        float v = rmx[rr];
        v = fmaxf(v, __shfl_xor(v, 1)); v = fmaxf(v, __shfl_xor(v, 2));
        v = fmaxf(v, __shfl_xor(v, 4));
        rmx[rr] = v;
    }
    if (colg == 0) {
        float* R = (kind == 0) ? Rxx : (kind == 1) ? Ryy : Rxy;
        const size_t base = ((size_t)b * T16 + J) * NN + (size_t)I * TB + r0;
#pragma unroll
        for (int rr = 0; rr < 4; rr++)
            R[base + rr] = acos_raw(fminf(fmaxf(rmx[rr], -CLIP), CLIP));
    }
    if (kind == 2) {
#pragma unroll
        for (int j = 0; j < 16; j++) {
            float v = cmx[j];
            v = fmaxf(v, __shfl_xor(v, 8)); v = fmaxf(v, __shfl_xor(v, 16));
            v = fmaxf(v, __shfl_xor(v, 32));
            cmx[j] = v;
        }
        if (rowg == 0) {
#pragma unroll
            for (int j = 0; j < 16; j++) colred[wv][colg + 8 * j] = cmx[j];
        }
        __syncthreads();
        if (t < TB) {
            const float v = fmaxf(fmaxf(colred[0][t], colred[1][t]),
                                  fmaxf(colred[2][t], colred[3][t]));
            Cxy[((size_t)b * T16 + I) * NN + (size_t)J * TB + t] =
                acos_raw(fminf(fmaxf(v, -CLIP), CLIP));
        }
    }
}

// ---------------------------------------------------------------------------
// Tile kernel (scalar — R6 inner loop; pk-FP32 regressed in round 9).
// ach computed once per pair; two exp2 serve the two reduction directions
// with per-row / per-col shifts. Partials stored TRANSPOSED: [slot][globalrow]
// so both the tile writes and the combine reads are coalesced.
// ---------------------------------------------------------------------------
struct TileArgs {
    const float* x; const float* y;
    const float* Wall; const float* Gall;
    const float* Rxx; const float* Ryy; const float* Rxy; const float* Cxy;
    float2* pAX; float2* pBY; float2* pAY; float2* pBX;
};

__global__ __launch_bounds__(256)
void tile_kernel(TileArgs A, float ieh, float pi_ieh)
{
    __shared__ float4 p1s[TB], p2s[TB];   // {px,py,pz,W}
    __shared__ float srs[TB], scs[TB];    // per-row / per-col shifts (scaled)
    __shared__ float colpart[4][TB];
    int kind, I, J; decode_tile(blockIdx.x, kind, I, J);
    const int b = blockIdx.y, t = threadIdx.x;
    const float* P1 = (kind == 1) ? A.y : A.x;
    const float* P2 = (kind == 0) ? A.x : A.y;
    const int o1 = (kind == 0) ? 0 : (kind == 1) ? 1 : 3;
    const int o2 = (kind == 0) ? 0 : (kind == 1) ? 1 : 2;
    float2* rowOut = (kind == 0) ? A.pAX : (kind == 1) ? A.pBY : A.pBX;
    float2* colOut = (kind == 0) ? A.pAX : (kind == 1) ? A.pBY : A.pAY;
    const bool diag = (kind < 2) && (I == J);
    const float* W1 = A.Wall + (size_t)o1 * SARR;
    const float* W2 = A.Wall + (size_t)o2 * SARR;
    const float* Rrow = (kind == 0) ? A.Rxx : (kind == 1) ? A.Ryy : A.Rxy;
    const float* Csrc = (kind == 0) ? A.Rxx : (kind == 1) ? A.Ryy : A.Cxy;

    // acos poly coefficients pre-scaled by ieh (log2 domain)
    const float K0 = 1.5707288f * ieh, K1 = -0.2121144f * ieh;
    const float K2 = 0.0742610f * ieh, K3 = -0.0187293f * ieh;

    if (t < TB) {
        size_t gi = (size_t)b * NN + (size_t)I * TB + t;
        p1s[t] = make_float4(P1[gi * 3], P1[gi * 3 + 1], P1[gi * 3 + 2], W1[gi]);
        srs[t] = Rrow[((size_t)b * T16 + J) * NN + (size_t)I * TB + t] * ieh;
    } else {
        int u = t - TB; size_t gi = (size_t)b * NN + (size_t)J * TB + u;
        p2s[u] = make_float4(P2[gi * 3], P2[gi * 3 + 1], P2[gi * 3 + 2], W2[gi]);
        scs[u] = Csrc[((size_t)b * T16 + I) * NN + (size_t)J * TB + u] * ieh;
    }
    const float G1 = A.Gall[o1 * 128 + b * T16 + I];
    const float G2 = A.Gall[o2 * 128 + b * T16 + J];
    __syncthreads();

    const int lane = t & 63, wv = t >> 6, colg = lane & 7, rowg = lane >> 3;
    const int r0 = wv * 32 + rowg * 4;
    float4 pr[4]; float srr[4];
#pragma unroll
    for (int rr = 0; rr < 4; rr++) { pr[rr] = p1s[r0 + rr]; srr[rr] = srs[r0 + rr]; }
    float racc[4] = {0.f, 0.f, 0.f, 0.f};
    float cacc[16];
#pragma unroll
    for (int j = 0; j < 16; j++) cacc[j] = 0.f;

#pragma unroll
    for (int j = 0; j < 16; j++) {
        const float4 q = p2s[colg + 8 * j];
        const float sc = scs[colg + 8 * j];
#pragma unroll
        for (int rr = 0; rr < 4; rr++) {
            const float4 p = pr[rr];
            float d = fmaf(p.x, q.x, fmaf(p.y, q.y, p.z * q.z));
            d = fminf(fmaxf(d, -CLIP), CLIP);
            const float u = fabsf(d);
            float pl = fmaf(u, K3, K2); pl = fmaf(u, pl, K1); pl = fmaf(u, pl, K0);
            const float rt = __builtin_amdgcn_sqrtf(1.f - u) * pl;
            const float ach = (d >= 0.f) ? rt : (pi_ieh - rt);
            racc[rr] = fmaf(q.w, __builtin_amdgcn_exp2f(srr[rr] - ach), racc[rr]);
            cacc[j]  = fmaf(p.w, __builtin_amdgcn_exp2f(sc - ach), cacc[j]);
        }
    }

    // col sums: reduce across rowg (lane bits 3..5)
#pragma unroll
    for (int j = 0; j < 16; j++) {
        float v = cacc[j];
        v += __shfl_xor(v, 8); v += __shfl_xor(v, 16); v += __shfl_xor(v, 32);
        cacc[j] = v;
    }
    if (rowg == 0) {
#pragma unroll
        for (int j = 0; j < 16; j++) colpart[wv][colg + 8 * j] = cacc[j];
    }
    // row sums: reduce across colg (lane bits 0..2)
#pragma unroll
    for (int rr = 0; rr < 4; rr++) {
        float v = racc[rr];
        v += __shfl_xor(v, 1); v += __shfl_xor(v, 2); v += __shfl_xor(v, 4);
        racc[rr] = v;
    }
    if (colg == 0) {
        // transposed layout: [slot J][global row] — 4 consecutive float2/lane
        const size_t gr = (size_t)J * SARR + (size_t)b * NN + (size_t)I * TB + r0;
#pragma unroll
        for (int rr = 0; rr < 4; rr++)
            rowOut[gr + rr] = make_float2(G2 - srr[rr], racc[rr]);
    }
    __syncthreads();
    if (!diag && t < TB) {
        const float v = colpart[0][t] + colpart[1][t] + colpart[2][t] + colpart[3][t];
        // transposed layout: [slot I][global row] — 128 consecutive float2/block
        const size_t gc = (size_t)I * SARR + (size_t)b * NN + (size_t)J * TB + t;
        colOut[gc] = make_float2(G1 - scs[t], v);
    }
}

// ---------------------------------------------------------------------------
// combine: merge 16 (M,S) partials per row (now coalesced: [slot][row]);
// r = -eps*ln2*(M+log2 S); optional 0.5-averaging; emit next-step W, G.
// ---------------------------------------------------------------------------
__global__ __launch_bounds__(256)
void combine_kernel(const float2* __restrict__ pAX, const float2* __restrict__ pBY,
                    const float2* __restrict__ pAY, const float2* __restrict__ pBX,
                    float* __restrict__ ax, float* __restrict__ by,
                    float* __restrict__ ay, float* __restrict__ bx,
                    const float* __restrict__ gxw, const float* __restrict__ gyw,
                    float* __restrict__ Wall, float* __restrict__ Gall,
                    float eps_ln2, float nieL2E, int do_avg)
{
    const int tid = threadIdx.x;
    const int gid = blockIdx.x * 256 + tid;
    const int o = gid >> 14, i = gid & (SARR - 1);
    const float2* P = (o == 0) ? pAX : (o == 1) ? pBY : (o == 2) ? pAY : pBX;
    float* pot = (o == 0) ? ax : (o == 1) ? by : (o == 2) ? ay : bx;
    float M = -INFINITY, S = 0.f;
#pragma unroll
    for (int u = 0; u < T16; u++) {
        const float2 pr = P[(size_t)u * SARR + i];
        if (pr.y > 0.f) {
            const float nm = fmaxf(M, pr.x);
            S = S * __builtin_amdgcn_exp2f(M - nm) + pr.y * __builtin_amdgcn_exp2f(pr.x - nm);
            M = nm;
        }
    }
    S = fmaxf(S, 1e-38f);
    float r = -eps_ln2 * (M + __builtin_amdgcn_logf(S));
    if (do_avg) r = 0.5f * (r + pot[i]);
    pot[i] = r;
    const float g = ((o == 0 || o == 3) ? gxw[i] : gyw[i]) + r * nieL2E;
    __shared__ float red[256];
    red[tid] = g;
    __syncthreads();
    const int base = tid & 128, loc = tid & 127;
    for (int st = 64; st; st >>= 1) {
        if (loc < st) red[base + loc] = fmaxf(red[base + loc], red[base + loc + st]);
        __syncthreads();
    }
    const float G = red[base];
    Wall[gid] = __builtin_amdgcn_exp2f(g - G);
    if (loc == 0) Gall[gid >> 7] = G;
}

// ---------------------------------------------------------------------------
__global__ __launch_bounds__(256)
void reduce_kernel(const float* __restrict__ alpha, const float* __restrict__ beta,
                   const float* __restrict__ a_x, const float* __restrict__ b_x,
                   const float* __restrict__ a_y, const float* __restrict__ b_y,
                   float* __restrict__ out)
{
    const int b = blockIdx.x, tid = threadIdx.x;
    float acc = 0.f;
    for (int n = tid; n < NN; n += 256) {
        const size_t i = (size_t)b * NN + n;
        acc += alpha[i] * (b_x[i] - a_x[i]);
        acc += beta[i] * (a_y[i] - b_y[i]);
    }
    __shared__ float red[256];
    red[tid] = acc;
    __syncthreads();
    for (int st = 128; st > 0; st >>= 1) {
        if (tid < st) red[tid] += red[tid + st];
        __syncthreads();
    }
    if (tid == 0) out[b] = red[0];
}

// ---------------------------------------------------------------------------
extern "C" void kernel_launch(void* const* d_in, const int* in_sizes, int n_in,
                              void* d_out, int out_size, void* d_ws, size_t ws_size,
                              hipStream_t stream)
{
    const float* alpha = (const float*)d_in[0];
    const float* x     = (const float*)d_in[1];
    const float* beta  = (const float*)d_in[2];
    const float* y     = (const float*)d_in[3];
    float* out = (float*)d_out;
    float* ws  = (float*)d_ws;

    const size_t S = SARR;
    float* gxw  = ws;
    float* gyw  = ws + S;
    float* ax   = ws + 2 * S;
    float* by   = ws + 3 * S;
    float* ay   = ws + 4 * S;
    float* bx   = ws + 5 * S;
    float* Wall = ws + 6 * S;              // 4*S
    float* Gall = ws + 10 * S;             // 512
    float* Rxx  = ws + 10 * S + 512;       // 16*S each (theta of max-dot)
    float* Ryy  = Rxx + 16 * S;
    float* Rxy  = Ryy + 16 * S;
    float* Cxy  = Rxy + 16 * S;
    float* pb   = Cxy + 16 * S;
    const size_t PSZ = (size_t)SARR * T16;
    float2* pAX = (float2*)pb;
    float2* pBY = pAX + PSZ;
    float2* pAY = pBY + PSZ;
    float2* pBX = pAY + PSZ;

    const float EPS[8] = {4.0f, 4.0f, 1.0f, 0.25f, 0.0625f, 0.015625f, 0.00390625f, 0.0025f};

    pack_kernel<<<(4 * SARR) / 256, 256, 0, stream>>>(alpha, beta, gxw, gyw, Wall, Gall);
    maxes_kernel<<<dim3(256, BB, 3), 256, 0, stream>>>(x, y, Rxx, Ryy, Rxy, Cxy);

    TileArgs TA;
    TA.x = x; TA.y = y; TA.Wall = Wall; TA.Gall = Gall;
    TA.Rxx = Rxx; TA.Ryy = Ryy; TA.Rxy = Rxy; TA.Cxy = Cxy;
    TA.pAX = pAX; TA.pBY = pBY; TA.pAY = pAY; TA.pBX = pBX;

    auto step = [&](float e, float next_e, int avg) {
        const float ieh = 0.5f * (1.f / e) * L2E;
        tile_kernel<<<dim3(NT, BB), 256, 0, stream>>>(TA, ieh, PI_F * ieh);
        combine_kernel<<<(4 * SARR) / 256, 256, 0, stream>>>(
            pAX, pBY, pAY, pBX, ax, by, ay, bx, gxw, gyw, Wall, Gall,
            e * LN2, (1.f / next_e) * L2E, avg);
    };

    step(EPS[0], EPS[0], 0);                                   // init
    for (int k = 0; k < 8; k++) step(EPS[k], (k < 7) ? EPS[k + 1] : EPS[7], 1);
    step(EPS[7], EPS[7], 0);                                   // final extrapolation

    reduce_kernel<<<BB, 256, 0, stream>>>(alpha, beta, ax, bx, ay, by, out);
}